// Round 18
// baseline (265.038 us; speedup 1.0000x reference)
//
#include <hip/hip_runtime.h>

#define HID 64
#define OUTD 5
#define BCAP 16384          // per-bucket edge capacity (padded mean ~12.3k)
#define PART_CHUNK 4096     // edges per partition block
#define CSTRIDE 16          // counter stride (ints): one counter per 64B line

typedef __attribute__((ext_vector_type(8))) short bf16x8;
typedef __attribute__((ext_vector_type(4))) float f32x4;

// split fp32 -> (hi, lo) bf16 bits (truncation; residual exact)
__device__ inline void split_bf16(float x, short& hi, short& lo) {
    unsigned u = __float_as_uint(x);
    unsigned h = u >> 16;
    float hf = __uint_as_float(h << 16);
    float lof = x - hf;                 // exact
    unsigned l = __float_as_uint(lof) >> 16;
    hi = (short)h; lo = (short)l;
}

__device__ inline ushort f2bf(float x) {          // RNE fp32->bf16
    unsigned u = __float_as_uint(x);
    u += 0x7fffu + ((u >> 16) & 1u);
    return (ushort)(u >> 16);
}

// ------- prep: counters=0 (line-padded), W1/W2 -> split-bf16 MFMA B-fragments ------------
__global__ void k_prep(const float* __restrict__ W1, const float* __restrict__ W2,
                       short* __restrict__ w1hi, short* __restrict__ w1lo,
                       short* __restrict__ w2hi, short* __restrict__ w2lo,
                       int* __restrict__ gcursor, int nbuck,
                       int* __restrict__ binCnt, int* __restrict__ binCur) {
    int gid = blockIdx.x * blockDim.x + threadIdx.x;
    if (gid < nbuck) gcursor[gid * CSTRIDE] = 0;
    if (gid < 64) { binCnt[gid * CSTRIDE] = 0; binCur[gid * CSTRIDE] = 0; }
    if (gid >= 32768 + 4096) return;
    int which = (gid >= 32768);
    int g = which ? gid - 32768 : gid;
    const float* W = which ? W2 : W1;
    short* ph = which ? w2hi : w1hi;
    short* pl = which ? w2lo : w1lo;
    int b = g & 7, lane = (g >> 3) & 63, c = (g >> 9) & 3, s = g >> 11;
    int k = s * 32 + 8 * (lane >> 4) + b;
    int j = c * 16 + (lane & 15);
    float x = W[k * 64 + j];
    short hi, lo; split_bf16(x, hi, lo);
    ph[g] = hi; pl[g] = lo;
}

// ---------------- GEMM1 standalone: C[M,64](bf16) = A[M,512](f32) @ Wfrag ----------------
__global__ __launch_bounds__(256) void k_gemm1(const float* __restrict__ A,
                                               const short* __restrict__ whi,
                                               const short* __restrict__ wlo,
                                               ushort* __restrict__ C, int M) {
    const int K = 512, NS = 16;
    int tid = threadIdx.x;
    int lane = tid & 63;
    int wave = tid >> 6;
    int r0 = blockIdx.x * 128 + wave * 32;

    int ar0 = r0 + (lane & 15);      if (ar0 >= M) ar0 = M - 1;
    int ar1 = r0 + 16 + (lane & 15); if (ar1 >= M) ar1 = M - 1;
    const float* pa0 = A + (size_t)ar0 * K + 8 * (lane >> 4);
    const float* pa1 = A + (size_t)ar1 * K + 8 * (lane >> 4);
    const bf16x8* bh = (const bf16x8*)whi + lane;
    const bf16x8* bl = (const bf16x8*)wlo + lane;

    f32x4 acc[2][4];
    #pragma unroll
    for (int r = 0; r < 2; r++)
        #pragma unroll
        for (int c = 0; c < 4; c++) acc[r][c] = (f32x4){0.f, 0.f, 0.f, 0.f};

    #pragma unroll
    for (int s = 0; s < NS; s++) {
        float4 x0 = *(const float4*)(pa0 + s * 32);
        float4 x1 = *(const float4*)(pa0 + s * 32 + 4);
        float4 y0 = *(const float4*)(pa1 + s * 32);
        float4 y1 = *(const float4*)(pa1 + s * 32 + 4);
        float xs[8] = {x0.x, x0.y, x0.z, x0.w, x1.x, x1.y, x1.z, x1.w};
        float ys[8] = {y0.x, y0.y, y0.z, y0.w, y1.x, y1.y, y1.z, y1.w};
        bf16x8 ah0, al0, ah1, al1;
        #pragma unroll
        for (int e = 0; e < 8; e++) {
            short h, l;
            split_bf16(xs[e], h, l); ah0[e] = h; al0[e] = l;
            split_bf16(ys[e], h, l); ah1[e] = h; al1[e] = l;
        }
        #pragma unroll
        for (int c = 0; c < 4; c++) {
            bf16x8 wh = bh[(s * 4 + c) * 64];
            bf16x8 wl = bl[(s * 4 + c) * 64];
            acc[0][c] = __builtin_amdgcn_mfma_f32_16x16x32_bf16(ah0, wh, acc[0][c], 0, 0, 0);
            acc[0][c] = __builtin_amdgcn_mfma_f32_16x16x32_bf16(ah0, wl, acc[0][c], 0, 0, 0);
            acc[0][c] = __builtin_amdgcn_mfma_f32_16x16x32_bf16(al0, wh, acc[0][c], 0, 0, 0);
            acc[1][c] = __builtin_amdgcn_mfma_f32_16x16x32_bf16(ah1, wh, acc[1][c], 0, 0, 0);
            acc[1][c] = __builtin_amdgcn_mfma_f32_16x16x32_bf16(ah1, wl, acc[1][c], 0, 0, 0);
            acc[1][c] = __builtin_amdgcn_mfma_f32_16x16x32_bf16(al1, wh, acc[1][c], 0, 0, 0);
        }
    }

    #pragma unroll
    for (int r = 0; r < 2; r++) {
        #pragma unroll
        for (int reg = 0; reg < 4; reg++) {
            int grow = r0 + r * 16 + 4 * (lane >> 4) + reg;
            if (grow < M) {
                #pragma unroll
                for (int c = 0; c < 4; c++)
                    C[(size_t)grow * 64 + c * 16 + (lane & 15)] = f2bf(acc[r][c][reg]);
            }
        }
    }
}

// ---------------- partition standalone: edges -> bucket streams ----------------
__global__ __launch_bounds__(256) void k_part(const int* __restrict__ row,
                                              const int* __restrict__ col,
                                              const float* __restrict__ ea,
                                              int* __restrict__ gcursor,
                                              int2* __restrict__ bucket_mem,
                                              int nbuck, int E) {
    __shared__ int hist[256];
    __shared__ int basearr[256];
    int t = threadIdx.x;
    int e0 = blockIdx.x * PART_CHUNK;
    if (t < nbuck) hist[t] = 0;
    __syncthreads();
    int cols[PART_CHUNK / 256];
    #pragma unroll
    for (int i = 0; i < PART_CHUNK / 256; i++) {
        int e = e0 + t + i * 256;
        cols[i] = (e < E) ? col[e] : -1;
        if (cols[i] >= 0) atomicAdd(&hist[cols[i] >> 9], 1);
    }
    __syncthreads();
    if (t < nbuck) {
        basearr[t] = atomicAdd(&gcursor[t * CSTRIDE], hist[t]);   // line-padded counter
        hist[t] = 0;                   // reuse as local cursor
    }
    __syncthreads();
    #pragma unroll
    for (int i = 0; i < PART_CHUNK / 256; i++) {
        int e = e0 + t + i * 256;
        if (e < E) {
            int c = cols[i];
            int b = c >> 9;
            int pos = basearr[b] + atomicAdd(&hist[b], 1);
            if (pos < BCAP) {
                int pack = ((c & 511) << 17) | row[e];
                bucket_mem[(size_t)b * BCAP + pos] = make_int2(pack, __float_as_int(ea[e]));
            }
        }
    }
}

// ------- build: per-bucket compact CSR (x16-padded, min 16) + dinv + used + bin hist -----
__global__ __launch_bounds__(256) void k_build(const int* __restrict__ gcursor,
                                               const int2* __restrict__ bucket_mem,
                                               int2* __restrict__ edges,
                                               int2* __restrict__ nodemeta,
                                               float* __restrict__ dinv,
                                               int* __restrict__ used,
                                               int* __restrict__ binCnt, int n) {
    __shared__ int hcnt[512];
    __shared__ int hoff[512];
    __shared__ float hdeg[512];
    __shared__ int ps[256];
    __shared__ int hbin[64];
    int b = blockIdx.x;
    int t = threadIdx.x;
    int cntb = gcursor[b * CSTRIDE]; if (cntb > BCAP) cntb = BCAP;
    const int2* bm = bucket_mem + (size_t)b * BCAP;

    #pragma unroll
    for (int l = t; l < 512; l += 256) { hcnt[l] = 0; hdeg[l] = 0.f; }
    if (t < 64) hbin[t] = 0;
    __syncthreads();
    for (int i = t; i < cntb; i += 256) atomicAdd(&hcnt[bm[i].x >> 17], 1);
    __syncthreads();
    // exclusive scan of PADDED counts: pc = max(16, (cnt+15)&~15)
    int c0 = hcnt[2 * t], c1 = hcnt[2 * t + 1];
    int q0 = (c0 + 15) & ~15; if (q0 < 16) q0 = 16;
    int q1 = (c1 + 15) & ~15; if (q1 < 16) q1 = 16;
    ps[t] = q0 + q1;
    __syncthreads();
    for (int o = 1; o < 256; o <<= 1) {
        int v = (t >= o) ? ps[t - o] : 0;
        __syncthreads();
        ps[t] += v;
        __syncthreads();
    }
    int excl = ps[t] - (q0 + q1);
    hoff[2 * t] = excl;
    hoff[2 * t + 1] = excl + q0;
    if (t == 255) used[b] = ps[255];
    __syncthreads();
    #pragma unroll
    for (int l = t; l < 512; l += 256) hcnt[l] = 0;   // reuse as cursor
    __syncthreads();
    for (int i = t; i < cntb; i += 256) {
        int2 eM = bm[i];
        int local = eM.x >> 17;
        int src = eM.x & 0x1FFFF;
        int p = hoff[local] + atomicAdd(&hcnt[local], 1);
        edges[(size_t)b * BCAP + p] = make_int2(src, eM.y);
        atomicAdd(&hdeg[local], __int_as_float(eM.y));
    }
    __syncthreads();
    #pragma unroll
    for (int l = t; l < 512; l += 256) {
        int node = b * 512 + l;
        if (node < n) {
            int cnt = hcnt[l];
            int pc = (cnt + 15) & ~15; if (pc < 16) pc = 16;
            for (int p2 = cnt; p2 < pc; p2++)
                edges[(size_t)b * BCAP + hoff[l] + p2] = make_int2(node, 0);
            nodemeta[node] = make_int2(b * BCAP + hoff[l], pc);
            dinv[node] = rsqrtf(hdeg[l] + 1.0f);     // + self-loop weight
            int bin = pc >> 4; if (bin > 63) bin = 63;
            atomicAdd(&hbin[bin], 1);
        }
    }
    __syncthreads();
    if (t < 64 && hbin[t] > 0) atomicAdd(&binCnt[t * CSTRIDE], hbin[t]);  // line-padded
}

// ------- norm (slot-parallel) + bin exclusive scan (extra last block) ----------
__global__ void k_norm2(int2* __restrict__ edges, const float* __restrict__ dinv,
                        const int* __restrict__ used, int n, int nbuck, int gNorm,
                        const int* __restrict__ binCnt, int* __restrict__ binBase) {
    if (blockIdx.x == (unsigned)gNorm) {
        if (threadIdx.x == 0) {
            int acc = 0;
            for (int i = 0; i < 64; i++) { binBase[i] = acc; acc += binCnt[i * CSTRIDE]; }
        }
        return;
    }
    int gid = blockIdx.x * blockDim.x + threadIdx.x;
    int b = gid >> 14;                 // BCAP = 16384
    if (b >= nbuck) return;
    int slot = gid & (BCAP - 1);
    if (slot >= used[b]) return;
    size_t idx = (size_t)b * BCAP + slot;
    int2 c = edges[idx];
    if ((unsigned)c.x < (unsigned)n) {
        c.y = __float_as_int(dinv[c.x] * __int_as_float(c.y));
        edges[idx] = c;
    }
}

// ------- scatter: perm = nodes counting-sorted by padded-degree bin ----------
__global__ void k_scatter(const int2* __restrict__ nodemeta, const int* __restrict__ binBase,
                          int* __restrict__ binCur, int* __restrict__ perm, int n) {
    __shared__ int lh[64];
    __shared__ int gb[64];
    int t = threadIdx.x;
    if (t < 64) lh[t] = 0;
    __syncthreads();
    int i = blockIdx.x * 256 + t;
    int bin = 0, r = 0;
    bool v = (i < n);
    if (v) {
        int pc = nodemeta[i].y;
        bin = pc >> 4; if (bin > 63) bin = 63;
        r = atomicAdd(&lh[bin], 1);
    }
    __syncthreads();
    if (t < 64) gb[t] = (lh[t] > 0) ? atomicAdd(&binCur[t * CSTRIDE], lh[t]) : 0;  // padded
    __syncthreads();
    if (v) perm[binBase[bin] + gb[bin] + r] = i;
}

// ------- conv gather: 4 nodes/wave via degree-sorted perm, 4 dims/lane (uint2) -----------
// FC==0: bf16 out a1 [n,64];  FC==1: fused  relu(conv) @ Wfc + bfc  -> fp32 [n,5]
template<int FC>
__global__ void k_gather4(const ushort* __restrict__ h, const int2* __restrict__ nodemeta,
                          const int2* __restrict__ edges, const float* __restrict__ dinv,
                          const int* __restrict__ perm,
                          const float* __restrict__ bias, const float* __restrict__ Wfc,
                          const float* __restrict__ bfc, ushort* __restrict__ outb,
                          float* __restrict__ outf, int n) {
    int gw = (blockIdx.x * blockDim.x + threadIdx.x) >> 6;
    int lane = threadIdx.x & 63;
    int s = lane & 15;               // dim quad index
    int idx = gw * 4 + (lane >> 4);
    bool valid = (idx < n);
    if (!valid) idx = n - 1;
    int node = perm[idx];            // uniform within 16-lane group

    int2 meta = nodemeta[node];
    int cnt = meta.y;                // multiple of 16, >= 16
    const int2* seg = edges + meta.x;
    uint2 self_u = *(const uint2*)&h[(size_t)node * 64 + 4 * s];
    float dvc = dinv[node];
    int mc = max(cnt, __shfl_xor(cnt, 16));
    mc = max(mc, __shfl_xor(mc, 32));    // wave-uniform max count (sorted -> ~cnt)

    float a0 = 0.f, a1 = 0.f, a2 = 0.f, a3 = 0.f;
    for (int i = 0; i < mc; i += 16) {
        int base = (i < cnt) ? i : (cnt - 16);   // dead rounds replay last real batch
        float live = (i < cnt) ? 1.f : 0.f;
        int4 m[8];
        #pragma unroll
        for (int q = 0; q < 8; q++) m[q] = *(const int4*)(seg + base + 2 * q);
        uint2 v[16];
        #pragma unroll
        for (int q = 0; q < 8; q++) {
            v[2 * q]     = *(const uint2*)&h[(size_t)m[q].x * 64 + 4 * s];
            v[2 * q + 1] = *(const uint2*)&h[(size_t)m[q].z * 64 + 4 * s];
        }
        #pragma unroll
        for (int q = 0; q < 8; q++) {
            float w0 = __int_as_float(m[q].y) * live;
            float w1 = __int_as_float(m[q].w) * live;
            uint2 va = v[2 * q], vb = v[2 * q + 1];
            a0 += w0 * __uint_as_float(va.x << 16);
            a1 += w0 * __uint_as_float(va.x & 0xffff0000u);
            a2 += w0 * __uint_as_float(va.y << 16);
            a3 += w0 * __uint_as_float(va.y & 0xffff0000u);
            a0 += w1 * __uint_as_float(vb.x << 16);
            a1 += w1 * __uint_as_float(vb.x & 0xffff0000u);
            a2 += w1 * __uint_as_float(vb.y << 16);
            a3 += w1 * __uint_as_float(vb.y & 0xffff0000u);
        }
    }

    float4 bv = *(const float4*)&bias[4 * s];
    float dd = dvc * dvc;
    float r0 = fmaxf(dvc * a0 + dd * __uint_as_float(self_u.x << 16) + bv.x, 0.f);
    float r1 = fmaxf(dvc * a1 + dd * __uint_as_float(self_u.x & 0xffff0000u) + bv.y, 0.f);
    float r2 = fmaxf(dvc * a2 + dd * __uint_as_float(self_u.y << 16) + bv.z, 0.f);
    float r3 = fmaxf(dvc * a3 + dd * __uint_as_float(self_u.y & 0xffff0000u) + bv.w, 0.f);

    if (FC == 0) {
        if (valid) {
            uint lo = ((uint)f2bf(r1) << 16) | (uint)f2bf(r0);
            uint hi = ((uint)f2bf(r3) << 16) | (uint)f2bf(r2);
            *(uint2*)&outb[(size_t)node * 64 + 4 * s] = make_uint2(lo, hi);
        }
    } else {
        #pragma unroll
        for (int j = 0; j < OUTD; j++) {
            float p = r0 * Wfc[(4 * s) * OUTD + j] + r1 * Wfc[(4 * s + 1) * OUTD + j]
                    + r2 * Wfc[(4 * s + 2) * OUTD + j] + r3 * Wfc[(4 * s + 3) * OUTD + j];
            #pragma unroll
            for (int o = 1; o <= 8; o <<= 1) p += __shfl_xor(p, o);  // 16-lane group sum
            if (s == j && valid) outf[(size_t)node * OUTD + j] = p + bfc[j];
        }
    }
}

// ---------------- GEMM2: C[M,64](bf16) = A[M,64](bf16) @ W2frag (2-term MFMA) ------------
__global__ __launch_bounds__(256) void k_gemm2(const ushort* __restrict__ A,
                                               const short* __restrict__ whi,
                                               const short* __restrict__ wlo,
                                               ushort* __restrict__ C, int M) {
    int tid = threadIdx.x;
    int lane = tid & 63;
    int wave = tid >> 6;
    int r0 = blockIdx.x * 128 + wave * 32;

    int ar0 = r0 + (lane & 15);      if (ar0 >= M) ar0 = M - 1;
    int ar1 = r0 + 16 + (lane & 15); if (ar1 >= M) ar1 = M - 1;
    const ushort* pa0 = A + (size_t)ar0 * 64 + 8 * (lane >> 4);
    const ushort* pa1 = A + (size_t)ar1 * 64 + 8 * (lane >> 4);
    const bf16x8* bh = (const bf16x8*)whi + lane;
    const bf16x8* bl = (const bf16x8*)wlo + lane;

    f32x4 acc[2][4];
    #pragma unroll
    for (int r = 0; r < 2; r++)
        #pragma unroll
        for (int c = 0; c < 4; c++) acc[r][c] = (f32x4){0.f, 0.f, 0.f, 0.f};

    #pragma unroll
    for (int s = 0; s < 2; s++) {
        bf16x8 a0 = *(const bf16x8*)(pa0 + s * 32);
        bf16x8 a1 = *(const bf16x8*)(pa1 + s * 32);
        #pragma unroll
        for (int c = 0; c < 4; c++) {
            bf16x8 wh = bh[(s * 4 + c) * 64];
            bf16x8 wl = bl[(s * 4 + c) * 64];
            acc[0][c] = __builtin_amdgcn_mfma_f32_16x16x32_bf16(a0, wh, acc[0][c], 0, 0, 0);
            acc[0][c] = __builtin_amdgcn_mfma_f32_16x16x32_bf16(a0, wl, acc[0][c], 0, 0, 0);
            acc[1][c] = __builtin_amdgcn_mfma_f32_16x16x32_bf16(a1, wh, acc[1][c], 0, 0, 0);
            acc[1][c] = __builtin_amdgcn_mfma_f32_16x16x32_bf16(a1, wl, acc[1][c], 0, 0, 0);
        }
    }

    #pragma unroll
    for (int r = 0; r < 2; r++) {
        #pragma unroll
        for (int reg = 0; reg < 4; reg++) {
            int grow = r0 + r * 16 + 4 * (lane >> 4) + reg;
            if (grow < M) {
                #pragma unroll
                for (int c = 0; c < 4; c++)
                    C[(size_t)grow * 64 + c * 16 + (lane & 15)] = f2bf(acc[r][c][reg]);
            }
        }
    }
}

extern "C" void kernel_launch(void* const* d_in, const int* in_sizes, int n_in,
                              void* d_out, int out_size, void* d_ws, size_t ws_size,
                              hipStream_t stream) {
    const float* x   = (const float*)d_in[0];
    const int*   ei  = (const int*)d_in[1];
    const float* ea  = (const float*)d_in[2];
    const float* W1  = (const float*)d_in[3];
    const float* b1  = (const float*)d_in[4];
    const float* W2  = (const float*)d_in[5];
    const float* b2  = (const float*)d_in[6];
    const float* Wfc = (const float*)d_in[7];
    const float* bfc = (const float*)d_in[8];

    const int N = in_sizes[0] / 512;   // 100000
    const int E = in_sizes[1] / 2;     // 1600000
    const int nbuck = (N + 511) >> 9;  // 196

    const int* row = ei;
    const int* col = ei + E;

    // ---- workspace carve ----
    uintptr_t p = (uintptr_t)d_ws;
    auto carve = [&](size_t bytes) -> void* {
        void* r = (void*)p;
        p += (bytes + 255) & ~(size_t)255;
        return r;
    };
    int*    gcursor    = (int*)carve((size_t)nbuck * CSTRIDE * 4);  // line-padded counters
    int*    used       = (int*)carve((size_t)nbuck * 4);
    int*    binCnt     = (int*)carve(64 * CSTRIDE * 4);             // line-padded
    int*    binCur     = (int*)carve(64 * CSTRIDE * 4);             // line-padded
    int*    binBase    = (int*)carve(64 * 4);
    int*    perm       = (int*)carve((size_t)N * 4);
    float*  dinv       = (float*)carve((size_t)N * 4);
    int2*   nodemeta   = (int2*)carve((size_t)N * 8);
    int2*   bucket_mem = (int2*)carve((size_t)nbuck * BCAP * 8);
    int2*   edges      = (int2*)carve((size_t)nbuck * BCAP * 8);
    short*  w1hi       = (short*)carve(32768 * 2);
    short*  w1lo       = (short*)carve(32768 * 2);
    short*  w2hi       = (short*)carve(4096 * 2);
    short*  w2lo       = (short*)carve(4096 * 2);
    ushort* hbuf       = (ushort*)carve((size_t)N * 64 * 2);   // bf16 h1 / h2
    ushort* abuf       = (ushort*)carve((size_t)N * 64 * 2);   // bf16 a1
    (void)ws_size;

    const int B = 256;
    int gGemm = (N + 127) / 128;                    // 782
    int gPart = (E + PART_CHUNK - 1) / PART_CHUNK;  // 391
    int gNorm = nbuck * (BCAP / B);                 // slot-parallel norm blocks
    int gGath = (((N + 3) / 4) * 64 + B - 1) / B;   // 4 nodes per wave
    int gScat = (N + B - 1) / B;
    int gPrep = (32768 + 4096 + B - 1) / B;

    // 1. counters=0 + W-fragment prep
    k_prep<<<gPrep, B, 0, stream>>>(W1, W2, w1hi, w1lo, w2hi, w2lo,
                                    gcursor, nbuck, binCnt, binCur);
    // 2a. partition standalone (MEASUREMENT SPLIT: attribute fused1's 115 us)
    k_part<<<gPart, B, 0, stream>>>(row, col, ea, gcursor, bucket_mem, nbuck, E);
    // 2b. GEMM1 standalone
    k_gemm1<<<gGemm, B, 0, stream>>>(x, w1hi, w1lo, hbuf, N);
    // 3. per-bucket compact CSR + dinv + used + degree-bin histogram
    k_build<<<nbuck, B, 0, stream>>>(gcursor, bucket_mem, edges, nodemeta,
                                     dinv, used, binCnt, N);
    // 4. edges.y <- dinv[src]*w (slot-parallel)  +  bin exclusive scan (last block)
    k_norm2<<<gNorm + 1, B, 0, stream>>>(edges, dinv, used, N, nbuck, gNorm,
                                         binCnt, binBase);
    // 5. perm = counting sort of nodes by padded degree
    k_scatter<<<gScat, B, 0, stream>>>(nodemeta, binBase, binCur, perm, N);
    // 6. a1 = relu(conv1)  (bf16 out, degree-sorted schedule)
    k_gather4<0><<<gGath, B, 0, stream>>>(hbuf, nodemeta, edges, dinv, perm, b1,
                                          nullptr, nullptr, abuf, nullptr, N);
    // 7. h2 = a1 @ W2  (bf16 A, 2-term MFMA)
    k_gemm2<<<gGemm, B, 0, stream>>>(abuf, w2hi, w2lo, hbuf, N);
    // 8. out = relu(conv2) @ Wfc + bfc (fused head)
    k_gather4<1><<<gGath, B, 0, stream>>>(hbuf, nodemeta, edges, dinv, perm, b2,
                                          Wfc, bfc, nullptr, (float*)d_out, N);
}

// Round 19
// 230.707 us; speedup vs baseline: 1.1488x; 1.1488x over previous
//
#include <hip/hip_runtime.h>

#define HID 64
#define OUTD 5
#define BCAP 16384          // per-bucket edge capacity (padded mean ~12.3k)
#define PART_CHUNK 4096     // edges per partition block
#define CSTRIDE 16          // counter stride (ints): one counter per 64B line

typedef __attribute__((ext_vector_type(8))) short bf16x8;
typedef __attribute__((ext_vector_type(4))) float f32x4;

// split fp32 -> (hi, lo) bf16 bits (truncation; residual exact)
__device__ inline void split_bf16(float x, short& hi, short& lo) {
    unsigned u = __float_as_uint(x);
    unsigned h = u >> 16;
    float hf = __uint_as_float(h << 16);
    float lof = x - hf;                 // exact
    unsigned l = __float_as_uint(lof) >> 16;
    hi = (short)h; lo = (short)l;
}

__device__ inline ushort f2bf(float x) {          // RNE fp32->bf16
    unsigned u = __float_as_uint(x);
    u += 0x7fffu + ((u >> 16) & 1u);
    return (ushort)(u >> 16);
}

// ------- prep: counters=0 (line-padded), W1/W2 -> split-bf16 MFMA B-fragments ------------
__global__ void k_prep(const float* __restrict__ W1, const float* __restrict__ W2,
                       short* __restrict__ w1hi, short* __restrict__ w1lo,
                       short* __restrict__ w2hi, short* __restrict__ w2lo,
                       int* __restrict__ gcursor, int nbuck,
                       int* __restrict__ binCnt, int* __restrict__ binCur) {
    int gid = blockIdx.x * blockDim.x + threadIdx.x;
    if (gid < nbuck) gcursor[gid * CSTRIDE] = 0;
    if (gid < 64) { binCnt[gid * CSTRIDE] = 0; binCur[gid * CSTRIDE] = 0; }
    if (gid >= 32768 + 4096) return;
    int which = (gid >= 32768);
    int g = which ? gid - 32768 : gid;
    const float* W = which ? W2 : W1;
    short* ph = which ? w2hi : w1hi;
    short* pl = which ? w2lo : w1lo;
    int b = g & 7, lane = (g >> 3) & 63, c = (g >> 9) & 3, s = g >> 11;
    int k = s * 32 + 8 * (lane >> 4) + b;
    int j = c * 16 + (lane & 15);
    float x = W[k * 64 + j];
    short hi, lo; split_bf16(x, hi, lo);
    ph[g] = hi; pl[g] = lo;
}

// -------- GEMM1 body: LDS-tiled (coalesced streaming loads + XOR-swizzled tile) ----------
// C[M,64](bf16) = A[M,512](f32) @ Wfrag. Tile = 128 rows x 32 k (16 KB). 16 tiles.
// Swizzle: float4-slot (row, c4) stored at row*8 + (c4 ^ (row&7)) -> conflict-free reads.
__device__ inline void gemm1_body(const float* __restrict__ A,
                                  const short* __restrict__ whi,
                                  const short* __restrict__ wlo,
                                  ushort* __restrict__ C, int M, int bid, int tid,
                                  float* __restrict__ As) {
    const int K = 512;
    int lane = tid & 63;
    int wave = tid >> 6;
    int r0 = bid * 128;

    const bf16x8* bh = (const bf16x8*)whi + lane;
    const bf16x8* bl = (const bf16x8*)wlo + lane;

    f32x4 acc[2][4];
    #pragma unroll
    for (int r = 0; r < 2; r++)
        #pragma unroll
        for (int c = 0; c < 4; c++) acc[r][c] = (f32x4){0.f, 0.f, 0.f, 0.f};

    int lr0 = wave * 32 + (lane & 15);       // this wave's row-frag rows
    int lr1 = lr0 + 16;
    int cb = 2 * (lane >> 4);                // float4-pair base within 32-k tile

    for (int s = 0; s < 16; s++) {           // 16 K-tiles of 32
        int k0 = s * 32;
        __syncthreads();                     // protect previous tile's reads
        #pragma unroll
        for (int i = 0; i < 4; i++) {
            int sl = i * 256 + tid;          // 0..1023 float4 slots
            int row = sl >> 3, c4 = sl & 7;
            int gr = r0 + row; if (gr >= M) gr = M - 1;
            float4 v = *(const float4*)(A + (size_t)gr * K + k0 + c4 * 4);
            *(float4*)&As[(size_t)(row * 8 + (c4 ^ (row & 7))) * 4] = v;
        }
        __syncthreads();

        float4 x0 = *(const float4*)&As[(size_t)(lr0 * 8 + ((cb)     ^ (lr0 & 7))) * 4];
        float4 x1 = *(const float4*)&As[(size_t)(lr0 * 8 + ((cb + 1) ^ (lr0 & 7))) * 4];
        float4 y0 = *(const float4*)&As[(size_t)(lr1 * 8 + ((cb)     ^ (lr1 & 7))) * 4];
        float4 y1 = *(const float4*)&As[(size_t)(lr1 * 8 + ((cb + 1) ^ (lr1 & 7))) * 4];
        float xs[8] = {x0.x, x0.y, x0.z, x0.w, x1.x, x1.y, x1.z, x1.w};
        float ys[8] = {y0.x, y0.y, y0.z, y0.w, y1.x, y1.y, y1.z, y1.w};
        bf16x8 ah0, al0, ah1, al1;
        #pragma unroll
        for (int e = 0; e < 8; e++) {
            short h, l;
            split_bf16(xs[e], h, l); ah0[e] = h; al0[e] = l;
            split_bf16(ys[e], h, l); ah1[e] = h; al1[e] = l;
        }
        #pragma unroll
        for (int c = 0; c < 4; c++) {
            bf16x8 wh = bh[(s * 4 + c) * 64];
            bf16x8 wl = bl[(s * 4 + c) * 64];
            acc[0][c] = __builtin_amdgcn_mfma_f32_16x16x32_bf16(ah0, wh, acc[0][c], 0, 0, 0);
            acc[0][c] = __builtin_amdgcn_mfma_f32_16x16x32_bf16(ah0, wl, acc[0][c], 0, 0, 0);
            acc[0][c] = __builtin_amdgcn_mfma_f32_16x16x32_bf16(al0, wh, acc[0][c], 0, 0, 0);
            acc[1][c] = __builtin_amdgcn_mfma_f32_16x16x32_bf16(ah1, wh, acc[1][c], 0, 0, 0);
            acc[1][c] = __builtin_amdgcn_mfma_f32_16x16x32_bf16(ah1, wl, acc[1][c], 0, 0, 0);
            acc[1][c] = __builtin_amdgcn_mfma_f32_16x16x32_bf16(al1, wh, acc[1][c], 0, 0, 0);
        }
    }

    int wr0 = r0 + wave * 32;
    #pragma unroll
    for (int r = 0; r < 2; r++) {
        #pragma unroll
        for (int reg = 0; reg < 4; reg++) {
            int grow = wr0 + r * 16 + 4 * (lane >> 4) + reg;
            if (grow < M) {
                #pragma unroll
                for (int c = 0; c < 4; c++)
                    C[(size_t)grow * 64 + c * 16 + (lane & 15)] = f2bf(acc[r][c][reg]);
            }
        }
    }
}

// ---------------- fused1: GEMM1 (blocks [0,gGemm)) || bucket partition (rest) ------------
__global__ __launch_bounds__(256) void k_fused1(const float* __restrict__ x,
                                                const short* __restrict__ w1hi,
                                                const short* __restrict__ w1lo,
                                                ushort* __restrict__ h1, int M, int gGemm,
                                                const int* __restrict__ row,
                                                const int* __restrict__ col,
                                                const float* __restrict__ ea,
                                                int* __restrict__ gcursor,
                                                int2* __restrict__ bucket_mem,
                                                int nbuck, int E) {
    __shared__ __align__(16) char ldsbuf[128 * 32 * 4];   // 16 KB, shared by both paths
    int bid = blockIdx.x;
    int t = threadIdx.x;
    if (bid < gGemm) {
        gemm1_body(x, w1hi, w1lo, h1, M, bid, t, (float*)ldsbuf);
        return;
    }
    int* hist = (int*)ldsbuf;            // [0,256)
    int* basearr = (int*)ldsbuf + 256;   // [256,512)
    int e0 = (bid - gGemm) * PART_CHUNK;
    if (t < nbuck) hist[t] = 0;
    __syncthreads();
    int cols[PART_CHUNK / 256];
    #pragma unroll
    for (int i = 0; i < PART_CHUNK / 256; i++) {
        int e = e0 + t + i * 256;
        cols[i] = (e < E) ? col[e] : -1;
        if (cols[i] >= 0) atomicAdd(&hist[cols[i] >> 9], 1);
    }
    __syncthreads();
    if (t < nbuck) {
        basearr[t] = atomicAdd(&gcursor[t * CSTRIDE], hist[t]);   // line-padded counter
        hist[t] = 0;                   // reuse as local cursor
    }
    __syncthreads();
    #pragma unroll
    for (int i = 0; i < PART_CHUNK / 256; i++) {
        int e = e0 + t + i * 256;
        if (e < E) {
            int c = cols[i];
            int b = c >> 9;
            int pos = basearr[b] + atomicAdd(&hist[b], 1);
            if (pos < BCAP) {
                int pack = ((c & 511) << 17) | row[e];
                bucket_mem[(size_t)b * BCAP + pos] = make_int2(pack, __float_as_int(ea[e]));
            }
        }
    }
}

// ------- build: per-bucket compact CSR (x16-padded, min 16) + dinv + used + bin hist -----
__global__ __launch_bounds__(256) void k_build(const int* __restrict__ gcursor,
                                               const int2* __restrict__ bucket_mem,
                                               int2* __restrict__ edges,
                                               int2* __restrict__ nodemeta,
                                               float* __restrict__ dinv,
                                               int* __restrict__ used,
                                               int* __restrict__ binCnt, int n) {
    __shared__ int hcnt[512];
    __shared__ int hoff[512];
    __shared__ float hdeg[512];
    __shared__ int ps[256];
    __shared__ int hbin[64];
    int b = blockIdx.x;
    int t = threadIdx.x;
    int cntb = gcursor[b * CSTRIDE]; if (cntb > BCAP) cntb = BCAP;
    const int2* bm = bucket_mem + (size_t)b * BCAP;

    #pragma unroll
    for (int l = t; l < 512; l += 256) { hcnt[l] = 0; hdeg[l] = 0.f; }
    if (t < 64) hbin[t] = 0;
    __syncthreads();
    for (int i = t; i < cntb; i += 256) atomicAdd(&hcnt[bm[i].x >> 17], 1);
    __syncthreads();
    // exclusive scan of PADDED counts: pc = max(16, (cnt+15)&~15)
    int c0 = hcnt[2 * t], c1 = hcnt[2 * t + 1];
    int q0 = (c0 + 15) & ~15; if (q0 < 16) q0 = 16;
    int q1 = (c1 + 15) & ~15; if (q1 < 16) q1 = 16;
    ps[t] = q0 + q1;
    __syncthreads();
    for (int o = 1; o < 256; o <<= 1) {
        int v = (t >= o) ? ps[t - o] : 0;
        __syncthreads();
        ps[t] += v;
        __syncthreads();
    }
    int excl = ps[t] - (q0 + q1);
    hoff[2 * t] = excl;
    hoff[2 * t + 1] = excl + q0;
    if (t == 255) used[b] = ps[255];
    __syncthreads();
    #pragma unroll
    for (int l = t; l < 512; l += 256) hcnt[l] = 0;   // reuse as cursor
    __syncthreads();
    for (int i = t; i < cntb; i += 256) {
        int2 eM = bm[i];
        int local = eM.x >> 17;
        int src = eM.x & 0x1FFFF;
        int p = hoff[local] + atomicAdd(&hcnt[local], 1);
        edges[(size_t)b * BCAP + p] = make_int2(src, eM.y);
        atomicAdd(&hdeg[local], __int_as_float(eM.y));
    }
    __syncthreads();
    #pragma unroll
    for (int l = t; l < 512; l += 256) {
        int node = b * 512 + l;
        if (node < n) {
            int cnt = hcnt[l];
            int pc = (cnt + 15) & ~15; if (pc < 16) pc = 16;
            for (int p2 = cnt; p2 < pc; p2++)
                edges[(size_t)b * BCAP + hoff[l] + p2] = make_int2(node, 0);
            nodemeta[node] = make_int2(b * BCAP + hoff[l], pc);
            dinv[node] = rsqrtf(hdeg[l] + 1.0f);     // + self-loop weight
            int bin = pc >> 4; if (bin > 63) bin = 63;
            atomicAdd(&hbin[bin], 1);
        }
    }
    __syncthreads();
    if (t < 64 && hbin[t] > 0) atomicAdd(&binCnt[t * CSTRIDE], hbin[t]);  // line-padded
}

// ------- norm (slot-parallel) + bin exclusive scan (extra last block) ----------
__global__ void k_norm2(int2* __restrict__ edges, const float* __restrict__ dinv,
                        const int* __restrict__ used, int n, int nbuck, int gNorm,
                        const int* __restrict__ binCnt, int* __restrict__ binBase) {
    if (blockIdx.x == (unsigned)gNorm) {
        if (threadIdx.x == 0) {
            int acc = 0;
            for (int i = 0; i < 64; i++) { binBase[i] = acc; acc += binCnt[i * CSTRIDE]; }
        }
        return;
    }
    int gid = blockIdx.x * blockDim.x + threadIdx.x;
    int b = gid >> 14;                 // BCAP = 16384
    if (b >= nbuck) return;
    int slot = gid & (BCAP - 1);
    if (slot >= used[b]) return;
    size_t idx = (size_t)b * BCAP + slot;
    int2 c = edges[idx];
    if ((unsigned)c.x < (unsigned)n) {
        c.y = __float_as_int(dinv[c.x] * __int_as_float(c.y));
        edges[idx] = c;
    }
}

// ------- scatter: perm = nodes counting-sorted by padded-degree bin ----------
__global__ void k_scatter(const int2* __restrict__ nodemeta, const int* __restrict__ binBase,
                          int* __restrict__ binCur, int* __restrict__ perm, int n) {
    __shared__ int lh[64];
    __shared__ int gb[64];
    int t = threadIdx.x;
    if (t < 64) lh[t] = 0;
    __syncthreads();
    int i = blockIdx.x * 256 + t;
    int bin = 0, r = 0;
    bool v = (i < n);
    if (v) {
        int pc = nodemeta[i].y;
        bin = pc >> 4; if (bin > 63) bin = 63;
        r = atomicAdd(&lh[bin], 1);
    }
    __syncthreads();
    if (t < 64) gb[t] = (lh[t] > 0) ? atomicAdd(&binCur[t * CSTRIDE], lh[t]) : 0;  // padded
    __syncthreads();
    if (v) perm[binBase[bin] + gb[bin] + r] = i;
}

// ------- conv gather: 4 nodes/wave via degree-sorted perm, 4 dims/lane (uint2) -----------
// FC==0: bf16 out a1 [n,64];  FC==1: fused  relu(conv) @ Wfc + bfc  -> fp32 [n,5]
template<int FC>
__global__ void k_gather4(const ushort* __restrict__ h, const int2* __restrict__ nodemeta,
                          const int2* __restrict__ edges, const float* __restrict__ dinv,
                          const int* __restrict__ perm,
                          const float* __restrict__ bias, const float* __restrict__ Wfc,
                          const float* __restrict__ bfc, ushort* __restrict__ outb,
                          float* __restrict__ outf, int n) {
    int gw = (blockIdx.x * blockDim.x + threadIdx.x) >> 6;
    int lane = threadIdx.x & 63;
    int s = lane & 15;               // dim quad index
    int idx = gw * 4 + (lane >> 4);
    bool valid = (idx < n);
    if (!valid) idx = n - 1;
    int node = perm[idx];            // uniform within 16-lane group

    int2 meta = nodemeta[node];
    int cnt = meta.y;                // multiple of 16, >= 16
    const int2* seg = edges + meta.x;
    uint2 self_u = *(const uint2*)&h[(size_t)node * 64 + 4 * s];
    float dvc = dinv[node];
    int mc = max(cnt, __shfl_xor(cnt, 16));
    mc = max(mc, __shfl_xor(mc, 32));    // wave-uniform max count (sorted -> ~cnt)

    float a0 = 0.f, a1 = 0.f, a2 = 0.f, a3 = 0.f;
    for (int i = 0; i < mc; i += 16) {
        int base = (i < cnt) ? i : (cnt - 16);   // dead rounds replay last real batch
        float live = (i < cnt) ? 1.f : 0.f;
        int4 m[8];
        #pragma unroll
        for (int q = 0; q < 8; q++) m[q] = *(const int4*)(seg + base + 2 * q);
        uint2 v[16];
        #pragma unroll
        for (int q = 0; q < 8; q++) {
            v[2 * q]     = *(const uint2*)&h[(size_t)m[q].x * 64 + 4 * s];
            v[2 * q + 1] = *(const uint2*)&h[(size_t)m[q].z * 64 + 4 * s];
        }
        #pragma unroll
        for (int q = 0; q < 8; q++) {
            float w0 = __int_as_float(m[q].y) * live;
            float w1 = __int_as_float(m[q].w) * live;
            uint2 va = v[2 * q], vb = v[2 * q + 1];
            a0 += w0 * __uint_as_float(va.x << 16);
            a1 += w0 * __uint_as_float(va.x & 0xffff0000u);
            a2 += w0 * __uint_as_float(va.y << 16);
            a3 += w0 * __uint_as_float(va.y & 0xffff0000u);
            a0 += w1 * __uint_as_float(vb.x << 16);
            a1 += w1 * __uint_as_float(vb.x & 0xffff0000u);
            a2 += w1 * __uint_as_float(vb.y << 16);
            a3 += w1 * __uint_as_float(vb.y & 0xffff0000u);
        }
    }

    float4 bv = *(const float4*)&bias[4 * s];
    float dd = dvc * dvc;
    float r0 = fmaxf(dvc * a0 + dd * __uint_as_float(self_u.x << 16) + bv.x, 0.f);
    float r1 = fmaxf(dvc * a1 + dd * __uint_as_float(self_u.x & 0xffff0000u) + bv.y, 0.f);
    float r2 = fmaxf(dvc * a2 + dd * __uint_as_float(self_u.y << 16) + bv.z, 0.f);
    float r3 = fmaxf(dvc * a3 + dd * __uint_as_float(self_u.y & 0xffff0000u) + bv.w, 0.f);

    if (FC == 0) {
        if (valid) {
            uint lo = ((uint)f2bf(r1) << 16) | (uint)f2bf(r0);
            uint hi = ((uint)f2bf(r3) << 16) | (uint)f2bf(r2);
            *(uint2*)&outb[(size_t)node * 64 + 4 * s] = make_uint2(lo, hi);
        }
    } else {
        #pragma unroll
        for (int j = 0; j < OUTD; j++) {
            float p = r0 * Wfc[(4 * s) * OUTD + j] + r1 * Wfc[(4 * s + 1) * OUTD + j]
                    + r2 * Wfc[(4 * s + 2) * OUTD + j] + r3 * Wfc[(4 * s + 3) * OUTD + j];
            #pragma unroll
            for (int o = 1; o <= 8; o <<= 1) p += __shfl_xor(p, o);  // 16-lane group sum
            if (s == j && valid) outf[(size_t)node * OUTD + j] = p + bfc[j];
        }
    }
}

// ---------------- GEMM2: C[M,64](bf16) = A[M,64](bf16) @ W2frag (2-term MFMA) ------------
__global__ __launch_bounds__(256) void k_gemm2(const ushort* __restrict__ A,
                                               const short* __restrict__ whi,
                                               const short* __restrict__ wlo,
                                               ushort* __restrict__ C, int M) {
    int tid = threadIdx.x;
    int lane = tid & 63;
    int wave = tid >> 6;
    int r0 = blockIdx.x * 128 + wave * 32;

    int ar0 = r0 + (lane & 15);      if (ar0 >= M) ar0 = M - 1;
    int ar1 = r0 + 16 + (lane & 15); if (ar1 >= M) ar1 = M - 1;
    const ushort* pa0 = A + (size_t)ar0 * 64 + 8 * (lane >> 4);
    const ushort* pa1 = A + (size_t)ar1 * 64 + 8 * (lane >> 4);
    const bf16x8* bh = (const bf16x8*)whi + lane;
    const bf16x8* bl = (const bf16x8*)wlo + lane;

    f32x4 acc[2][4];
    #pragma unroll
    for (int r = 0; r < 2; r++)
        #pragma unroll
        for (int c = 0; c < 4; c++) acc[r][c] = (f32x4){0.f, 0.f, 0.f, 0.f};

    #pragma unroll
    for (int s = 0; s < 2; s++) {
        bf16x8 a0 = *(const bf16x8*)(pa0 + s * 32);
        bf16x8 a1 = *(const bf16x8*)(pa1 + s * 32);
        #pragma unroll
        for (int c = 0; c < 4; c++) {
            bf16x8 wh = bh[(s * 4 + c) * 64];
            bf16x8 wl = bl[(s * 4 + c) * 64];
            acc[0][c] = __builtin_amdgcn_mfma_f32_16x16x32_bf16(a0, wh, acc[0][c], 0, 0, 0);
            acc[0][c] = __builtin_amdgcn_mfma_f32_16x16x32_bf16(a0, wl, acc[0][c], 0, 0, 0);
            acc[1][c] = __builtin_amdgcn_mfma_f32_16x16x32_bf16(a1, wh, acc[1][c], 0, 0, 0);
            acc[1][c] = __builtin_amdgcn_mfma_f32_16x16x32_bf16(a1, wl, acc[1][c], 0, 0, 0);
        }
    }

    #pragma unroll
    for (int r = 0; r < 2; r++) {
        #pragma unroll
        for (int reg = 0; reg < 4; reg++) {
            int grow = r0 + r * 16 + 4 * (lane >> 4) + reg;
            if (grow < M) {
                #pragma unroll
                for (int c = 0; c < 4; c++)
                    C[(size_t)grow * 64 + c * 16 + (lane & 15)] = f2bf(acc[r][c][reg]);
            }
        }
    }
}

extern "C" void kernel_launch(void* const* d_in, const int* in_sizes, int n_in,
                              void* d_out, int out_size, void* d_ws, size_t ws_size,
                              hipStream_t stream) {
    const float* x   = (const float*)d_in[0];
    const int*   ei  = (const int*)d_in[1];
    const float* ea  = (const float*)d_in[2];
    const float* W1  = (const float*)d_in[3];
    const float* b1  = (const float*)d_in[4];
    const float* W2  = (const float*)d_in[5];
    const float* b2  = (const float*)d_in[6];
    const float* Wfc = (const float*)d_in[7];
    const float* bfc = (const float*)d_in[8];

    const int N = in_sizes[0] / 512;   // 100000
    const int E = in_sizes[1] / 2;     // 1600000
    const int nbuck = (N + 511) >> 9;  // 196

    const int* row = ei;
    const int* col = ei + E;

    // ---- workspace carve ----
    uintptr_t p = (uintptr_t)d_ws;
    auto carve = [&](size_t bytes) -> void* {
        void* r = (void*)p;
        p += (bytes + 255) & ~(size_t)255;
        return r;
    };
    int*    gcursor    = (int*)carve((size_t)nbuck * CSTRIDE * 4);  // line-padded counters
    int*    used       = (int*)carve((size_t)nbuck * 4);
    int*    binCnt     = (int*)carve(64 * CSTRIDE * 4);             // line-padded
    int*    binCur     = (int*)carve(64 * CSTRIDE * 4);             // line-padded
    int*    binBase    = (int*)carve(64 * 4);
    int*    perm       = (int*)carve((size_t)N * 4);
    float*  dinv       = (float*)carve((size_t)N * 4);
    int2*   nodemeta   = (int2*)carve((size_t)N * 8);
    int2*   bucket_mem = (int2*)carve((size_t)nbuck * BCAP * 8);
    int2*   edges      = (int2*)carve((size_t)nbuck * BCAP * 8);
    short*  w1hi       = (short*)carve(32768 * 2);
    short*  w1lo       = (short*)carve(32768 * 2);
    short*  w2hi       = (short*)carve(4096 * 2);
    short*  w2lo       = (short*)carve(4096 * 2);
    ushort* hbuf       = (ushort*)carve((size_t)N * 64 * 2);   // bf16 h1 / h2
    ushort* abuf       = (ushort*)carve((size_t)N * 64 * 2);   // bf16 a1
    (void)ws_size;

    const int B = 256;
    int gGemm = (N + 127) / 128;                    // 782
    int gPart = (E + PART_CHUNK - 1) / PART_CHUNK;  // 391
    int gNorm = nbuck * (BCAP / B);                 // slot-parallel norm blocks
    int gGath = (((N + 3) / 4) * 64 + B - 1) / B;   // 4 nodes per wave
    int gScat = (N + B - 1) / B;
    int gPrep = (32768 + 4096 + B - 1) / B;

    // 1. counters=0 + W-fragment prep
    k_prep<<<gPrep, B, 0, stream>>>(W1, W2, w1hi, w1lo, w2hi, w2lo,
                                    gcursor, nbuck, binCnt, binCur);
    // 2. fused: h1 = x @ W1 (LDS-tiled MFMA)  ||  bucket partition
    k_fused1<<<gGemm + gPart, B, 0, stream>>>(x, w1hi, w1lo, hbuf, N, gGemm,
                                              row, col, ea, gcursor, bucket_mem, nbuck, E);
    // 3. per-bucket compact CSR + dinv + used + degree-bin histogram
    k_build<<<nbuck, B, 0, stream>>>(gcursor, bucket_mem, edges, nodemeta,
                                     dinv, used, binCnt, N);
    // 4. edges.y <- dinv[src]*w (slot-parallel)  +  bin exclusive scan (last block)
    k_norm2<<<gNorm + 1, B, 0, stream>>>(edges, dinv, used, N, nbuck, gNorm,
                                         binCnt, binBase);
    // 5. perm = counting sort of nodes by padded degree
    k_scatter<<<gScat, B, 0, stream>>>(nodemeta, binBase, binCur, perm, N);
    // 6. a1 = relu(conv1)  (bf16 out, degree-sorted schedule)
    k_gather4<0><<<gGath, B, 0, stream>>>(hbuf, nodemeta, edges, dinv, perm, b1,
                                          nullptr, nullptr, abuf, nullptr, N);
    // 7. h2 = a1 @ W2  (bf16 A, 2-term MFMA)
    k_gemm2<<<gGemm, B, 0, stream>>>(abuf, w2hi, w2lo, hbuf, N);
    // 8. out = relu(conv2) @ Wfc + bfc (fused head)
    k_gather4<1><<<gGath, B, 0, stream>>>(hbuf, nodemeta, edges, dinv, perm, b2,
                                          Wfc, bfc, nullptr, (float*)d_out, N);
}